// Round 1
// baseline (261.230 us; speedup 1.0000x reference)
//
#include <hip/hip_runtime.h>

#define BATCH 256
#define NIN   1152
#define NOUT  10
#define DDIM  16
#define KPT   18   // NIN / 64 capsules per thread (each thread owns a d-quad)

// One block per (batch, out_capsule). 256 threads.
// Thread t: q = t&3 owns d in [4q, 4q+4); g = t>>2 owns capsules i = g + 64k, k<18.
// u_hat slice held in registers (18 float4 = 72 VGPRs); b, w, reductions in LDS.
__global__ __launch_bounds__(256)
void routing_kernel(const float* __restrict__ u_hat, float* __restrict__ out) {
    __shared__ float bsh[NIN];        // routing logits b_i
    __shared__ float wsh[NIN];        // exp(b_i - m)
    __shared__ float red[4 * DDIM];   // per-wave partial s
    __shared__ float vsh[DDIM];       // s then v
    __shared__ float scal[8];         // per-wave max / sum

    const int t    = threadIdx.x;
    const int q    = t & 3;
    const int g    = t >> 2;
    const int wave = t >> 6;
    const int lane = t & 63;

    // blockIdx.x = bb * NOUT + oo
    const int bb = blockIdx.x / NOUT;
    const int oo = blockIdx.x % NOUT;

    // u_hat flat index: ((bb*NIN + i)*NOUT + oo)*DDIM + d
    const float* base = u_hat + (size_t)bb * (NIN * NOUT * DDIM) + oo * DDIM + q * 4;

    float4 u[KPT];
#pragma unroll
    for (int k = 0; k < KPT; ++k) {
        const int i = g + 64 * k;
        u[k] = *reinterpret_cast<const float4*>(base + (size_t)i * (NOUT * DDIM));
    }

    for (int i = t; i < NIN; i += 256) bsh[i] = 0.0f;
    __syncthreads();

    for (int r = 0; r < 3; ++r) {
        // ---- softmax over n_in: max ----
        float m = -3.4e38f;
        for (int i = t; i < NIN; i += 256) m = fmaxf(m, bsh[i]);
        for (int off = 32; off >= 1; off >>= 1) m = fmaxf(m, __shfl_down(m, off));
        if (lane == 0) scal[wave] = m;
        __syncthreads();
        m = fmaxf(fmaxf(scal[0], scal[1]), fmaxf(scal[2], scal[3]));

        // ---- w = exp(b - m), Z = sum w ----
        float z = 0.0f;
        for (int i = t; i < NIN; i += 256) {
            const float w = __expf(bsh[i] - m);
            wsh[i] = w;
            z += w;
        }
        for (int off = 32; off >= 1; off >>= 1) z += __shfl_down(z, off);
        if (lane == 0) scal[4 + wave] = z;
        __syncthreads();
        const float invZ = 1.0f / (scal[4] + scal[5] + scal[6] + scal[7]);

        // ---- s_d = (1/Z) * sum_i w_i * u[i][d] ----
        float sx = 0.f, sy = 0.f, sz = 0.f, sw = 0.f;
#pragma unroll
        for (int k = 0; k < KPT; ++k) {
            const float w = wsh[g + 64 * k];
            sx += w * u[k].x; sy += w * u[k].y; sz += w * u[k].z; sw += w * u[k].w;
        }
        // reduce across the 16 groups of this wave (strides multiple of 4 keep q fixed)
        for (int off = 32; off >= 4; off >>= 1) {
            sx += __shfl_down(sx, off);
            sy += __shfl_down(sy, off);
            sz += __shfl_down(sz, off);
            sw += __shfl_down(sw, off);
        }
        if (lane < 4) {
            float* rp = &red[wave * DDIM + lane * 4];
            rp[0] = sx; rp[1] = sy; rp[2] = sz; rp[3] = sw;
        }
        __syncthreads();
        if (t < DDIM) {
            vsh[t] = (red[t] + red[DDIM + t] + red[2 * DDIM + t] + red[3 * DDIM + t]) * invZ;
        }
        __syncthreads();

        // ---- squash (redundant per-thread scalar math, 16 broadcast LDS reads) ----
        float sqr = 0.0f;
#pragma unroll
        for (int d = 0; d < DDIM; ++d) { const float sv = vsh[d]; sqr += sv * sv; }
        const float scale = sqr / ((1.0f + sqr) * sqrtf(sqr + 1e-7f));
        __syncthreads();
        if (t < DDIM) vsh[t] *= scale;
        __syncthreads();

        if (r == 2) break;

        // ---- agreement a_i = sum_d u[i][d]*v_d ; b_i += a_i ----
        const float vx = vsh[q * 4 + 0], vy = vsh[q * 4 + 1];
        const float vz = vsh[q * 4 + 2], vw = vsh[q * 4 + 3];
#pragma unroll
        for (int k = 0; k < KPT; ++k) {
            float a = u[k].x * vx + u[k].y * vy + u[k].z * vz + u[k].w * vw;
            a += __shfl_xor(a, 1);
            a += __shfl_xor(a, 2);
            if (q == 0) bsh[g + 64 * k] += a;
        }
        __syncthreads();
    }

    if (t < DDIM) {
        out[(size_t)blockIdx.x * DDIM + t] = vsh[t];
    }
}

extern "C" void kernel_launch(void* const* d_in, const int* in_sizes, int n_in,
                              void* d_out, int out_size, void* d_ws, size_t ws_size,
                              hipStream_t stream) {
    const float* u_hat = (const float*)d_in[0];
    float* out = (float*)d_out;
    routing_kernel<<<dim3(BATCH * NOUT), dim3(256), 0, stream>>>(u_hat, out);
}

// Round 3
// 260.673 us; speedup vs baseline: 1.0021x; 1.0021x over previous
//
#include <hip/hip_runtime.h>

#define BATCH 256
#define NIN   1152
#define NOUT  10
#define DDIM  16
#define KPT   18   // NIN / 64 capsules per thread (each thread owns a d-quad)

// R3: exact R1 compute structure (proven replay-stable) + XCD-aware block
// swizzle only. R2's r=0 softmax-skip / warm-LDS bsh write caused post-timing
// divergence; reverted.
// One block per (batch, out_capsule). 256 threads.
// Thread t: q = t&3 owns d in [4q,4q+4); g = t>>2 owns capsules i = g+64k, k<18.
// u_hat slice held in registers (18 float4 = 72 VGPRs); b, w, reductions in LDS.
__global__ __launch_bounds__(256)
void routing_kernel(const float* __restrict__ u_hat, float* __restrict__ out) {
    __shared__ float bsh[NIN];        // routing logits b_i
    __shared__ float wsh[NIN];        // exp(b_i - m)
    __shared__ float red[4 * DDIM];   // per-wave partial s
    __shared__ float vsh[DDIM];       // s then v
    __shared__ float scal[8];         // per-wave max / sum

    const int t    = threadIdx.x;
    const int q    = t & 3;
    const int g    = t >> 2;
    const int wave = t >> 6;
    const int lane = t & 63;

    // XCD-aware decode: 2560 blocks = 8 XCDs x 32 bb x 10 oo (bijective)
    const int x   = blockIdx.x;
    const int xcd = x & 7;
    const int j   = x >> 3;          // 0..319
    const int oo  = j % NOUT;
    const int bb  = xcd * 32 + j / NOUT;

    // u_hat flat index: ((bb*NIN + i)*NOUT + oo)*DDIM + d
    const float* base = u_hat + (size_t)bb * (NIN * NOUT * DDIM) + oo * DDIM + q * 4;

    float4 u[KPT];
#pragma unroll
    for (int k = 0; k < KPT; ++k) {
        const int i = g + 64 * k;
        u[k] = *reinterpret_cast<const float4*>(base + (size_t)i * (NOUT * DDIM));
    }

    for (int i = t; i < NIN; i += 256) bsh[i] = 0.0f;
    __syncthreads();

    for (int r = 0; r < 3; ++r) {
        // ---- softmax over n_in: max ----
        float m = -3.4e38f;
        for (int i = t; i < NIN; i += 256) m = fmaxf(m, bsh[i]);
        for (int off = 32; off >= 1; off >>= 1) m = fmaxf(m, __shfl_down(m, off));
        if (lane == 0) scal[wave] = m;
        __syncthreads();
        m = fmaxf(fmaxf(scal[0], scal[1]), fmaxf(scal[2], scal[3]));

        // ---- w = exp(b - m), Z = sum w ----
        float z = 0.0f;
        for (int i = t; i < NIN; i += 256) {
            const float w = __expf(bsh[i] - m);
            wsh[i] = w;
            z += w;
        }
        for (int off = 32; off >= 1; off >>= 1) z += __shfl_down(z, off);
        if (lane == 0) scal[4 + wave] = z;
        __syncthreads();
        const float invZ = 1.0f / (scal[4] + scal[5] + scal[6] + scal[7]);

        // ---- s_d = (1/Z) * sum_i w_i * u[i][d] ----
        float sx = 0.f, sy = 0.f, sz = 0.f, sw = 0.f;
#pragma unroll
        for (int k = 0; k < KPT; ++k) {
            const float w = wsh[g + 64 * k];
            sx += w * u[k].x; sy += w * u[k].y; sz += w * u[k].z; sw += w * u[k].w;
        }
        // reduce across the 16 groups of this wave (strides multiple of 4 keep q fixed)
        for (int off = 32; off >= 4; off >>= 1) {
            sx += __shfl_down(sx, off);
            sy += __shfl_down(sy, off);
            sz += __shfl_down(sz, off);
            sw += __shfl_down(sw, off);
        }
        if (lane < 4) {
            float* rp = &red[wave * DDIM + lane * 4];
            rp[0] = sx; rp[1] = sy; rp[2] = sz; rp[3] = sw;
        }
        __syncthreads();
        if (t < DDIM) {
            vsh[t] = (red[t] + red[DDIM + t] + red[2 * DDIM + t] + red[3 * DDIM + t]) * invZ;
        }
        __syncthreads();

        // ---- squash (redundant per-thread scalar math, 16 broadcast LDS reads) ----
        float sqr = 0.0f;
#pragma unroll
        for (int d = 0; d < DDIM; ++d) { const float sv = vsh[d]; sqr += sv * sv; }
        const float scale = sqr / ((1.0f + sqr) * sqrtf(sqr + 1e-7f));
        __syncthreads();
        if (t < DDIM) vsh[t] *= scale;
        __syncthreads();

        if (r == 2) break;

        // ---- agreement a_i = sum_d u[i][d]*v_d ; b_i += a_i ----
        const float vx = vsh[q * 4 + 0], vy = vsh[q * 4 + 1];
        const float vz = vsh[q * 4 + 2], vw = vsh[q * 4 + 3];
#pragma unroll
        for (int k = 0; k < KPT; ++k) {
            float a = u[k].x * vx + u[k].y * vy + u[k].z * vz + u[k].w * vw;
            a += __shfl_xor(a, 1);
            a += __shfl_xor(a, 2);
            if (q == 0) bsh[g + 64 * k] += a;
        }
        __syncthreads();
    }

    if (t < DDIM) {
        out[(size_t)(bb * NOUT + oo) * DDIM + t] = vsh[t];
    }
}

extern "C" void kernel_launch(void* const* d_in, const int* in_sizes, int n_in,
                              void* d_out, int out_size, void* d_ws, size_t ws_size,
                              hipStream_t stream) {
    const float* u_hat = (const float*)d_in[0];
    float* out = (float*)d_out;
    routing_kernel<<<dim3(BATCH * NOUT), dim3(256), 0, stream>>>(u_hat, out);
}